// Round 8
// baseline (329.835 us; speedup 1.0000x reference)
//
#include <hip/hip_runtime.h>
#include <math.h>

#define N_NODES 50000
#define N_EDGES 800000
#define IN_DIM 128
#define HIDDEN 128
#define CLASSES 64
#define N2 100000      // concatenated node space: graph1 [0,50000), graph2 [50000,100000)

#define BIN_SHIFT 8    // 256 nodes per bin
#define BIN_SZ 256
#define NB 391         // ceil(100000/256)
#define NBLK 256       // edge-partition blocks for P1/P2
#define CHUNK ((2 * N_EDGES + NBLK - 1) / NBLK)

static __device__ __forceinline__ float elu_f(float x) {
    return x > 0.f ? x : (expf(x) - 1.f);
}

static __device__ __forceinline__ void fma4(float4& a, const float4 w, const float s) {
    a.x = fmaf(w.x, s, a.x);
    a.y = fmaf(w.y, s, a.y);
    a.z = fmaf(w.z, s, a.z);
    a.w = fmaf(w.w, s, a.w);
}

// f32 -> bf16 (RNE) pack of two values into one uint (lo = first)
static __device__ __forceinline__ unsigned pack_bf2(float a, float b) {
    unsigned ua = __float_as_uint(a);
    ua = (ua + 0x7FFFu + ((ua >> 16) & 1u)) >> 16;
    unsigned ub = __float_as_uint(b);
    ub = (ub + 0x7FFFu + ((ub >> 16) & 1u)) >> 16;
    return ua | (ub << 16);
}

// unpack two bf16 (packed in uint) -> float2
static __device__ __forceinline__ float2 bf2f2(unsigned u) {
    float2 r;
    r.x = __uint_as_float(u << 16);
    r.y = __uint_as_float(u & 0xFFFF0000u);
    return r;
}

// ---------------------------------------------------------------------------
// P1: per-block LDS histogram over bins. counts[bin*NBLK + blk] (bin-major).
// ---------------------------------------------------------------------------
__global__ __launch_bounds__(1024) void k_p1_count(
    const int* __restrict__ dst1, const int* __restrict__ dst2,
    int* __restrict__ counts)
{
    __shared__ int hist[NB];
    const int t = threadIdx.x, b = blockIdx.x;
    if (t < NB) hist[t] = 0;
    __syncthreads();
    const int beg = b * CHUNK;
    const int end = min(beg + CHUNK, 2 * N_EDGES);
    for (int i = beg + t; i < end; i += 1024) {
        const int idx = (i < N_EDGES) ? dst1[i] : (N_NODES + dst2[i - N_EDGES]);
        atomicAdd(&hist[idx >> BIN_SHIFT], 1);
    }
    __syncthreads();
    if (t < NB) counts[t * NBLK + b] = hist[t];
}

// ---------------------------------------------------------------------------
// Scan: bin totals (contiguous int4 sums), exclusive scan over bins, and
// in-place rewrite counts -> per-(bin,blk) start cursors. One 512-thread block.
// ---------------------------------------------------------------------------
__global__ __launch_bounds__(512) void k_scan_bins(
    int* __restrict__ counts, int* __restrict__ binStart, int* __restrict__ off)
{
    __shared__ int tot[512];
    const int t = threadIdx.x;
    int total = 0;
    if (t < NB) {
        const int4* p = reinterpret_cast<const int4*>(counts + t * NBLK);
        #pragma unroll 8
        for (int i = 0; i < NBLK / 4; ++i) {
            const int4 c = p[i];
            total += (c.x + c.y) + (c.z + c.w);
        }
    }
    tot[t] = (t < NB) ? total : 0;
    __syncthreads();
    const int v = tot[t];
    for (int d = 1; d < 512; d <<= 1) {
        const int x = (t >= d) ? tot[t - d] : 0;
        __syncthreads();
        tot[t] += x;
        __syncthreads();
    }
    const int excl = tot[t] - v;
    if (t < NB) binStart[t] = excl;
    if (t == NB - 1) binStart[NB] = tot[t];      // == 2*N_EDGES
    if (t == 0) off[N2] = 2 * N_EDGES;           // CSR sentinel
    if (t < NB) {
        int run = excl;
        int* p = counts + t * NBLK;
        for (int i = 0; i < NBLK; i += 4) {
            int4 c = *reinterpret_cast<int4*>(p + i);
            int4 w;
            w.x = run; run += c.x;
            w.y = run; run += c.y;
            w.z = run; run += c.z;
            w.w = run; run += c.w;
            *reinterpret_cast<int4*>(p + i) = w;
        }
    }
}

// ---------------------------------------------------------------------------
// P2: scatter packed records into per-(bin,blk) contiguous sub-ranges.
// rec = (src << 8) | localDst   (src < 2^16, localDst < 256)
// ---------------------------------------------------------------------------
__global__ __launch_bounds__(1024) void k_p2_scatter(
    const int* __restrict__ src1, const int* __restrict__ dst1,
    const int* __restrict__ src2, const int* __restrict__ dst2,
    const int* __restrict__ counts, unsigned* __restrict__ binned)
{
    __shared__ int cur[NB];
    const int t = threadIdx.x, b = blockIdx.x;
    if (t < NB) cur[t] = counts[t * NBLK + b];
    __syncthreads();
    const int beg = b * CHUNK;
    const int end = min(beg + CHUNK, 2 * N_EDGES);
    for (int i = beg + t; i < end; i += 1024) {
        int s, idx;
        if (i < N_EDGES) { s = src1[i]; idx = dst1[i]; }
        else             { s = src2[i - N_EDGES]; idx = N_NODES + dst2[i - N_EDGES]; }
        const int bin = idx >> BIN_SHIFT;
        const unsigned rec = ((unsigned)s << BIN_SHIFT) | (unsigned)(idx & (BIN_SZ - 1));
        const int pos = atomicAdd(&cur[bin], 1);
        binned[pos] = rec;
    }
}

// ---------------------------------------------------------------------------
// P3: per-bin CSR build. LDS hist(256) + scan -> off; scatter srcs into the
// bin's contiguous csr window.
// ---------------------------------------------------------------------------
__global__ __launch_bounds__(1024) void k_p3_csr(
    const unsigned* __restrict__ binned, const int* __restrict__ binStart,
    int* __restrict__ off, int* __restrict__ csr)
{
    __shared__ int hist[BIN_SZ], sc[BIN_SZ], cur[BIN_SZ];
    const int t = threadIdx.x, bin = blockIdx.x;
    const int bs = binStart[bin], be = binStart[bin + 1];
    const int base = bin << BIN_SHIFT;
    const int nloc = min(BIN_SZ, N2 - base);
    if (t < BIN_SZ) hist[t] = 0;
    __syncthreads();
    for (int p = bs + t; p < be; p += 1024)
        atomicAdd(&hist[binned[p] & (BIN_SZ - 1u)], 1);
    __syncthreads();
    int v = 0;
    if (t < BIN_SZ) { v = hist[t]; sc[t] = v; }
    __syncthreads();
    for (int d = 1; d < BIN_SZ; d <<= 1) {
        int x = 0;
        if (t < BIN_SZ && t >= d) x = sc[t - d];
        __syncthreads();
        if (t < BIN_SZ) sc[t] += x;
        __syncthreads();
    }
    if (t < BIN_SZ) {
        const int excl = sc[t] - v;
        cur[t] = bs + excl;
        if (t < nloc) off[base + t] = bs + excl;
    }
    __syncthreads();
    for (int p = bs + t; p < be; p += 1024) {
        const unsigned rec = binned[p];
        const int pos = atomicAdd(&cur[rec & (BIN_SZ - 1u)], 1);
        csr[pos] = (int)(rec >> BIN_SHIFT);
    }
}

// ---------------------------------------------------------------------------
// GEMM 1: y1b = bf16( f @ W1^T )  (bias folded into pull epilogue)
// ---------------------------------------------------------------------------
__global__ __launch_bounds__(256) void k_gemm1(
    const float* __restrict__ f, const float* __restrict__ W1,
    unsigned short* __restrict__ y1b)
{
    __shared__ float Wt[IN_DIM][HIDDEN + 4];
    __shared__ float S[16][IN_DIM];

    const int t = threadIdx.x;
    for (int i = t; i < HIDDEN * IN_DIM; i += 256) {
        const int o = i >> 7, k = i & 127;
        Wt[k][o] = W1[i];
    }
    const int o4 = (t & 31) * 4;
    const int ln = t >> 5;

    const int ntiles = N_NODES / 16;  // 3125 exact
    for (int tile = blockIdx.x; tile < ntiles; tile += gridDim.x) {
        const int v0 = tile * 16;
        __syncthreads();
        for (int i = t; i < 16 * IN_DIM; i += 256) {
            const int r = i >> 7, k = i & 127;
            S[r][k] = f[(size_t)(v0 + r) * IN_DIM + k];
        }
        __syncthreads();

        float4 acc1 = {0.f, 0.f, 0.f, 0.f};
        float4 acc2 = {0.f, 0.f, 0.f, 0.f};
        const float* s1 = S[ln * 2];
        const float* s2 = S[ln * 2 + 1];
        #pragma unroll 8
        for (int k = 0; k < IN_DIM; k += 4) {
            const float4 sa = *reinterpret_cast<const float4*>(s1 + k);
            const float4 sb = *reinterpret_cast<const float4*>(s2 + k);
            const float4 w0 = *reinterpret_cast<const float4*>(&Wt[k + 0][o4]);
            const float4 w1 = *reinterpret_cast<const float4*>(&Wt[k + 1][o4]);
            const float4 w2 = *reinterpret_cast<const float4*>(&Wt[k + 2][o4]);
            const float4 w3 = *reinterpret_cast<const float4*>(&Wt[k + 3][o4]);
            fma4(acc1, w0, sa.x); fma4(acc1, w1, sa.y); fma4(acc1, w2, sa.z); fma4(acc1, w3, sa.w);
            fma4(acc2, w0, sb.x); fma4(acc2, w1, sb.y); fma4(acc2, w2, sb.z); fma4(acc2, w3, sb.w);
        }
        const int na = v0 + ln * 2, nb = na + 1;
        uint2 pa, pb;
        pa.x = pack_bf2(acc1.x, acc1.y); pa.y = pack_bf2(acc1.z, acc1.w);
        pb.x = pack_bf2(acc2.x, acc2.y); pb.y = pack_bf2(acc2.z, acc2.w);
        *reinterpret_cast<uint2*>(y1b + (size_t)na * HIDDEN + o4) = pa;
        *reinterpret_cast<uint2*>(y1b + (size_t)nb * HIDDEN + o4) = pb;
    }
}

// ---------------------------------------------------------------------------
// GEMM 2: y2b = bf16( x1 @ W2^T )
// ---------------------------------------------------------------------------
__global__ __launch_bounds__(256) void k_gemm2(
    const float* __restrict__ x1, const float* __restrict__ W2,
    unsigned short* __restrict__ y2b)
{
    __shared__ float Wt[IN_DIM][CLASSES + 4];
    __shared__ float S[32][IN_DIM];

    const int t = threadIdx.x;
    for (int i = t; i < CLASSES * IN_DIM; i += 256) {
        const int c = i >> 7, k = i & 127;
        Wt[k][c] = W2[i];
    }
    const int c4 = (t & 15) * 4;
    const int ln = t >> 4;

    const int ntiles = (N_NODES + 31) / 32;  // 1563
    for (int tile = blockIdx.x; tile < ntiles; tile += gridDim.x) {
        const int v0 = tile * 32;
        __syncthreads();
        for (int i = t; i < 32 * IN_DIM; i += 256) {
            const int r = i >> 7, k = i & 127;
            const int node = v0 + r;
            S[r][k] = (node < N_NODES) ? x1[(size_t)node * IN_DIM + k] : 0.f;
        }
        __syncthreads();

        float4 acc1 = {0.f, 0.f, 0.f, 0.f};
        float4 acc2 = {0.f, 0.f, 0.f, 0.f};
        const float* s1 = S[ln * 2];
        const float* s2 = S[ln * 2 + 1];
        #pragma unroll 8
        for (int k = 0; k < IN_DIM; k += 4) {
            const float4 sa = *reinterpret_cast<const float4*>(s1 + k);
            const float4 sb = *reinterpret_cast<const float4*>(s2 + k);
            const float4 w0 = *reinterpret_cast<const float4*>(&Wt[k + 0][c4]);
            const float4 w1 = *reinterpret_cast<const float4*>(&Wt[k + 1][c4]);
            const float4 w2 = *reinterpret_cast<const float4*>(&Wt[k + 2][c4]);
            const float4 w3 = *reinterpret_cast<const float4*>(&Wt[k + 3][c4]);
            fma4(acc1, w0, sa.x); fma4(acc1, w1, sa.y); fma4(acc1, w2, sa.z); fma4(acc1, w3, sa.w);
            fma4(acc2, w0, sb.x); fma4(acc2, w1, sb.y); fma4(acc2, w2, sb.z); fma4(acc2, w3, sb.w);
        }
        const int na = v0 + ln * 2, nb = na + 1;
        uint2 pa, pb;
        pa.x = pack_bf2(acc1.x, acc1.y); pa.y = pack_bf2(acc1.z, acc1.w);
        pb.x = pack_bf2(acc2.x, acc2.y); pb.y = pack_bf2(acc2.z, acc2.w);
        if (na < N_NODES) *reinterpret_cast<uint2*>(y2b + (size_t)na * CLASSES + c4) = pa;
        if (nb < N_NODES) *reinterpret_cast<uint2*>(y2b + (size_t)nb * CLASSES + c4) = pb;
    }
}

// ---------------------------------------------------------------------------
// Pull layer 1 (dim 128): one wave per node, lane holds 2 dims (uint = 2 bf16).
// deg loop in branch-free 8-wide chunks: clamped index + mask-FMA (no serial
// tail; 8 independent row loads in flight).
// ---------------------------------------------------------------------------
__global__ __launch_bounds__(256) void k_pull1(
    const unsigned short* __restrict__ y1b,
    const int* __restrict__ off, const int* __restrict__ csr,
    const float* __restrict__ b1, const float* __restrict__ attn,
    float* __restrict__ x1)
{
    const int lane = threadIdx.x & 63;
    const int v = (blockIdx.x * 256 + threadIdx.x) >> 6;
    if (v >= N_NODES) return;
    const int c = lane * 2;

    float2 acc1 = {0.f, 0.f}, acc2 = {0.f, 0.f};
    #pragma unroll
    for (int g = 0; g < 2; ++g) {
        const int idx = g * N_NODES + v;
        const int beg = off[idx], end_ = off[idx + 1];
        float2 acc = {0.f, 0.f};
        for (int j = beg; j < end_; j += 8) {
            #pragma unroll
            for (int u = 0; u < 8; ++u) {
                const int jj = j + u;
                const int s = csr[min(jj, end_ - 1)];
                const float2 r = bf2f2(*reinterpret_cast<const unsigned*>(
                    y1b + (size_t)s * HIDDEN + c));
                const float m = (jj < end_) ? 1.f : 0.f;
                acc.x = fmaf(m, r.x, acc.x);
                acc.y = fmaf(m, r.y, acc.y);
            }
        }
        if (g == 0) acc1 = acc; else acc2 = acc;
    }

    const float2 yv = bf2f2(*reinterpret_cast<const unsigned*>(y1b + (size_t)v * HIDDEN + c));
    const float2 bb = *reinterpret_cast<const float2*>(b1 + c);
    const float a0 = attn[0], a1 = attn[1];
    float2 r;
    r.x = elu_f(a0 * (yv.x + acc1.x + bb.x)) + elu_f(a1 * (yv.x + acc2.x + bb.x));
    r.y = elu_f(a0 * (yv.y + acc1.y + bb.y)) + elu_f(a1 * (yv.y + acc2.y + bb.y));
    *reinterpret_cast<float2*>(x1 + (size_t)v * HIDDEN + c) = r;
}

// ---------------------------------------------------------------------------
// Pull layer 2 (dim 64): one wave per node; half-wave per graph; shfl merge.
// Same 8-wide branch-free chunks.
// ---------------------------------------------------------------------------
__global__ __launch_bounds__(256) void k_pull2(
    const unsigned short* __restrict__ y2b,
    const int* __restrict__ off, const int* __restrict__ csr,
    const float* __restrict__ b2, const float* __restrict__ attn,
    float* __restrict__ out)
{
    const int lane = threadIdx.x & 63;
    const int v = (blockIdx.x * 256 + threadIdx.x) >> 6;
    if (v >= N_NODES) return;
    const int half = lane >> 5;
    const int l = lane & 31;
    const int c = l * 2;

    const int idx = half * N_NODES + v;
    const int beg = off[idx], end_ = off[idx + 1];
    float2 acc = {0.f, 0.f};
    for (int j = beg; j < end_; j += 8) {
        #pragma unroll
        for (int u = 0; u < 8; ++u) {
            const int jj = j + u;
            const int s = csr[min(jj, end_ - 1)];
            const float2 r = bf2f2(*reinterpret_cast<const unsigned*>(
                y2b + (size_t)s * CLASSES + c));
            const float m = (jj < end_) ? 1.f : 0.f;
            acc.x = fmaf(m, r.x, acc.x);
            acc.y = fmaf(m, r.y, acc.y);
        }
    }

    float2 other;
    other.x = __shfl(acc.x, lane ^ 32);
    other.y = __shfl(acc.y, lane ^ 32);
    const float2 g1 = (half == 0) ? acc : other;
    const float2 g2 = (half == 0) ? other : acc;

    const float2 yv = bf2f2(*reinterpret_cast<const unsigned*>(y2b + (size_t)v * CLASSES + c));
    const float2 bb = *reinterpret_cast<const float2*>(b2 + c);
    const float a0 = attn[0], a1 = attn[1];
    float2 r;
    r.x = elu_f(a0 * (yv.x + g1.x + bb.x)) + elu_f(a1 * (yv.x + g2.x + bb.x));
    r.y = elu_f(a0 * (yv.y + g1.y + bb.y)) + elu_f(a1 * (yv.y + g2.y + bb.y));
    if (half == 0)
        *reinterpret_cast<float2*>(out + (size_t)v * CLASSES + c) = r;
}

extern "C" void kernel_launch(void* const* d_in, const int* in_sizes, int n_in,
                              void* d_out, int out_size, void* d_ws, size_t ws_size,
                              hipStream_t stream)
{
    const float* features = (const float*)d_in[0];
    const float* W1   = (const float*)d_in[1];
    const float* b1   = (const float*)d_in[2];
    const float* W2   = (const float*)d_in[3];
    const float* b2   = (const float*)d_in[4];
    const float* attn = (const float*)d_in[5];
    const int* src1   = (const int*)d_in[6];
    const int* dst1   = (const int*)d_in[7];
    const int* src2   = (const int*)d_in[8];
    const int* dst2   = (const int*)d_in[9];
    float* out = (float*)d_out;

    // workspace layout (segments padded to 16 B multiples)
    float* x1 = (float*)d_ws;                                        // 6.4M f32
    unsigned short* y1b = (unsigned short*)(x1 + (size_t)N_NODES * HIDDEN);   // 6.4M bf16
    unsigned short* y2b = y1b + (size_t)N_NODES * HIDDEN;            // 3.2M bf16
    int* off      = (int*)(y2b + (size_t)N_NODES * CLASSES);         // N2+4 (padded)
    int* binStart = off + (N2 + 4);                                  // NB+1=392
    int* counts   = binStart + 392;                                  // NB*NBLK
    unsigned* binned = (unsigned*)(counts + NB * NBLK);              // 1.6M
    int* csr      = (int*)(binned + 2 * N_EDGES);                    // 1.6M

    // ---- binned CSR build (shared by both layers) ----
    k_p1_count  <<<NBLK, 1024, 0, stream>>>(dst1, dst2, counts);
    k_scan_bins <<<1, 512, 0, stream>>>(counts, binStart, off);
    k_p2_scatter<<<NBLK, 1024, 0, stream>>>(src1, dst1, src2, dst2, counts, binned);
    k_p3_csr    <<<NB, 1024, 0, stream>>>(binned, binStart, off, csr);

    // ---- layer 1 ----
    k_gemm1<<<1024, 256, 0, stream>>>(features, W1, y1b);
    k_pull1<<<12500, 256, 0, stream>>>(y1b, off, csr, b1, attn, x1);

    // ---- layer 2 ----
    k_gemm2<<<782, 256, 0, stream>>>(x1, W2, y2b);
    k_pull2<<<12500, 256, 0, stream>>>(y2b, off, csr, b2, attn, out);
}